// Round 7
// baseline (594.174 us; speedup 1.0000x reference)
//
#include <hip/hip_runtime.h>
#include <hip/hip_bf16.h>

#define DI __device__ __forceinline__

typedef short bf16x8_t __attribute__((ext_vector_type(8)));
typedef _Float16 f16x8_t __attribute__((ext_vector_type(8)));
typedef float f32x4_t __attribute__((ext_vector_type(4)));

DI unsigned short f2bf(float f) {
    unsigned u = __float_as_uint(f);
    u += 0x7fffu + ((u >> 16) & 1u);
    return (unsigned short)(u >> 16);
}
DI float bfu2f(unsigned short u) { return __uint_as_float(((unsigned)u) << 16); }
DI unsigned short f2h(float f) {
    _Float16 h = (_Float16)f;
    unsigned short u;
    __builtin_memcpy(&u, &h, 2);
    return u;
}
DI float h2f(unsigned short u) {
    _Float16 h;
    __builtin_memcpy(&h, &u, 2);
    return (float)h;
}
// pack 8 floats -> 2 b64 writes of bf16 at dp (8B aligned)
DI void pack8_bf16(const float* f, unsigned short* dp) {
    unsigned u[4];
#pragma unroll
    for (int j = 0; j < 4; ++j) {
        __hip_bfloat162 hh = __float22bfloat162_rn(make_float2(f[2 * j], f[2 * j + 1]));
        __builtin_memcpy(&u[j], &hh, 4);
    }
    *(unsigned long long*)dp = ((unsigned long long)u[1] << 32) | u[0];
    *(unsigned long long*)(dp + 4) = ((unsigned long long)u[3] << 32) | u[2];
}
DI bf16x8_t rd_frag36(const unsigned short* base, int row, int quad) {
    const unsigned short* p = base + row * 36 + quad * 8;
    union { unsigned long long d[2]; bf16x8_t v; } u;
    u.d[0] = *(const unsigned long long*)p;
    u.d[1] = *(const unsigned long long*)(p + 4);
    return u.v;
}
DI f16x8_t rd_frag36h(const char* p) {
    union { unsigned long long d[2]; f16x8_t v; } u;
    u.d[0] = *(const unsigned long long*)p;
    u.d[1] = *(const unsigned long long*)(p + 8);
    return u.v;
}

// ---------------------------------------------------------------------------
// Kernel 1: inverse channel norms. Grid (16 chunks, 72 = tensor*36+lb).
// Block: 64 pos x 4 c-groups of 128.
// ---------------------------------------------------------------------------
__global__ __launch_bounds__(256) void k_norms(const float* __restrict__ fqf,
                                               const float* __restrict__ fsf,
                                               float* __restrict__ rq,
                                               float* __restrict__ rs) {
    __shared__ float red[256];
    const int lb = blockIdx.y % 36;
    const int tensor = blockIdx.y / 36;
    const int p0 = blockIdx.x * 64;
    const int t = threadIdx.x;
    const int pl = t & 63, cg = t >> 6;
    const float* src = (tensor ? fsf : fqf) + (size_t)lb * 524288 + p0 + pl;
    float s = 0.f;
    for (int c = cg * 128; c < cg * 128 + 128; ++c) {
        float v = src[(size_t)c << 10];
        s += v * v;
    }
    red[t] = s;
    __syncthreads();
    if (t < 64) {
        float q = red[t] + red[t + 64] + red[t + 128] + red[t + 192];
        float* dst = tensor ? rs : rq;
        dst[lb * 1024 + p0 + t] = 1.f / fmaxf(sqrtf(q), 1e-12f);
    }
}

// ---------------------------------------------------------------------------
// Kernel 2 (MFMA): corr partials, 2-way level split. bf16 LDS tiles
// ([row][36] ush, 72B stride), conversion at staging, frags = 2x ds_read_b64.
// Grid (8,8,8). P01[lg*4+b][q][s] fp16.
// ---------------------------------------------------------------------------
__global__ __launch_bounds__(256) void k_corr(const float* __restrict__ fqf,
                                              const float* __restrict__ fsf,
                                              const float* __restrict__ rq,
                                              const float* __restrict__ rs,
                                              unsigned short* __restrict__ P01) {
    __shared__ __align__(16) unsigned short Abf[2][128 * 36];
    __shared__ __align__(16) unsigned short Bbf[2][128 * 36];
    const int b = blockIdx.z >> 1;
    const int lg = blockIdx.z & 1;
    const int q0 = blockIdx.y * 128;
    const int s0 = blockIdx.x * 128;
    const int t = threadIdx.x;
    const int w = t >> 6, lane = t & 63;
    const int wrow = w >> 1, wcol = w & 1;
    const int quad = lane >> 4, m16 = lane & 15;
    const int nsteps = (5 - lg) << 4;        // lg0: 80, lg1: 64
    const int sm = t & 127, so = t >> 7;     // staging: row, oct-pair selector

    f32x4_t zero4 = {0.f, 0.f, 0.f, 0.f};
    f32x4_t master[4][4], lvl[4][4];
#pragma unroll
    for (int i = 0; i < 4; ++i)
#pragma unroll
        for (int j = 0; j < 4; ++j) { master[i][j] = zero4; lvl[i][j] = zero4; }

    // stage one 32k x 128m tile: gbase points at [k=0][m=0] of the tile
    auto stage = [&](const float* gbase, unsigned short* dst) {
#pragma unroll
        for (int h = 0; h < 2; ++h) {
            int oct = so + 2 * h;
            float f[8];
#pragma unroll
            for (int j = 0; j < 8; ++j)
                f[j] = gbase[(size_t)(oct * 8 + j) * 1024 + sm];
            pack8_bf16(f, dst + sm * 36 + oct * 8);
        }
    };

    stage(fqf + (size_t)(lg * 4 + b) * 524288 + q0, &Abf[0][0]);
    stage(fsf + (size_t)(lg * 4 + b) * 524288 + s0, &Bbf[0][0]);

    for (int step = 0; step < nsteps; ++step) {
        const int buf = step & 1;
        __syncthreads();
        if (step < nsteps - 1) {
            int ns = step + 1;
            int lb = (lg + 2 * (ns >> 4)) * 4 + b;
            size_t koff = (size_t)((ns & 15) << 5) * 1024;
            stage(fqf + (size_t)lb * 524288 + koff + q0, &Abf[buf ^ 1][0]);
            stage(fsf + (size_t)lb * 524288 + koff + s0, &Bbf[buf ^ 1][0]);
        }
        bf16x8_t af[4], bfr[4];
#pragma unroll
        for (int i = 0; i < 4; ++i) {
            af[i]  = rd_frag36(&Abf[buf][0], wrow * 64 + i * 16 + m16, quad);
            bfr[i] = rd_frag36(&Bbf[buf][0], wcol * 64 + i * 16 + m16, quad);
        }
#pragma unroll
        for (int mi = 0; mi < 4; ++mi)
#pragma unroll
            for (int ni = 0; ni < 4; ++ni)
                lvl[mi][ni] = __builtin_amdgcn_mfma_f32_16x16x32_bf16(
                    af[mi], bfr[ni], lvl[mi][ni], 0, 0, 0);

        if ((step & 15) == 15) {
            int lb = (lg + 2 * (step >> 4)) * 4 + b;
            const float* rqb = rq + lb * 1024 + q0 + wrow * 64;
            const float* rsb = rs + lb * 1024 + s0 + wcol * 64;
            float rq4[4][4], rsv[4];
#pragma unroll
            for (int mi = 0; mi < 4; ++mi) {
                float4 v = *(const float4*)(rqb + mi * 16 + quad * 4);
                rq4[mi][0] = v.x; rq4[mi][1] = v.y; rq4[mi][2] = v.z; rq4[mi][3] = v.w;
            }
#pragma unroll
            for (int ni = 0; ni < 4; ++ni) rsv[ni] = rsb[ni * 16 + m16];
#pragma unroll
            for (int mi = 0; mi < 4; ++mi)
#pragma unroll
                for (int ni = 0; ni < 4; ++ni) {
#pragma unroll
                    for (int e = 0; e < 4; ++e)
                        master[mi][ni][e] += fmaxf(lvl[mi][ni][e] * rq4[mi][e] * rsv[ni], 0.f);
                    lvl[mi][ni] = zero4;
                }
        }
    }

#pragma unroll
    for (int mi = 0; mi < 4; ++mi)
#pragma unroll
        for (int e = 0; e < 4; ++e) {
            int q = q0 + wrow * 64 + mi * 16 + quad * 4 + e;
            unsigned short* cp = P01 + ((((size_t)(lg * 4 + b)) * 1024 + q) << 10)
                                 + s0 + wcol * 64 + m16;
#pragma unroll
            for (int ni = 0; ni < 4; ++ni)
                cp[ni * 16] = f2h(master[mi][ni][e]);
        }
}

// ---------------------------------------------------------------------------
// Kernel 3: softmax over s; writes attn as padded fp16 [b][sb(32)][q][36].
// ---------------------------------------------------------------------------
__global__ __launch_bounds__(256) void k_softmax(const unsigned short* __restrict__ P01,
                                                 unsigned short* __restrict__ attn) {
    __shared__ float red[8];
    const int row = blockIdx.x;  // 0..4095
    const int b = row >> 10, q = row & 1023;
    const int t = threadIdx.x;
    const unsigned short* p0 = P01 + (((size_t)b << 20) + ((size_t)q << 10)) + t * 4;
    const unsigned short* p1 = p0 + ((size_t)4 << 20);
    uint2 a0 = *(const uint2*)p0;
    uint2 a1 = *(const uint2*)p1;
    const float SC = 20.f / 9.f;
    float v0 = (h2f(a0.x & 0xffff) + h2f(a1.x & 0xffff)) * SC;
    float v1 = (h2f(a0.x >> 16)    + h2f(a1.x >> 16)) * SC;
    float v2 = (h2f(a0.y & 0xffff) + h2f(a1.y & 0xffff)) * SC;
    float v3 = (h2f(a0.y >> 16)    + h2f(a1.y >> 16)) * SC;
    float m = fmaxf(fmaxf(v0, v1), fmaxf(v2, v3));
#pragma unroll
    for (int off = 32; off >= 1; off >>= 1) m = fmaxf(m, __shfl_down(m, off));
    const int wid = t >> 6, lane = t & 63;
    if (lane == 0) red[wid] = m;
    __syncthreads();
    m = fmaxf(fmaxf(red[0], red[1]), fmaxf(red[2], red[3]));
    float e0 = __expf(v0 - m), e1 = __expf(v1 - m);
    float e2 = __expf(v2 - m), e3 = __expf(v3 - m);
    float s = e0 + e1 + e2 + e3;
#pragma unroll
    for (int off = 32; off >= 1; off >>= 1) s += __shfl_down(s, off);
    if (lane == 0) red[4 + wid] = s;
    __syncthreads();
    s = red[4] + red[5] + red[6] + red[7];
    float inv = 1.f / s;
    unsigned short* o = attn + (size_t)((b * 32 + (t >> 3)) * 1024 + q) * 36 + (t & 7) * 4;
    uint2 r;
    r.x = (unsigned)f2h(e0 * inv) | ((unsigned)f2h(e1 * inv) << 16);
    r.y = (unsigned)f2h(e2 * inv) | ((unsigned)f2h(e3 * inv) << 16);
    *(uint2*)o = r;
}

// ---------------------------------------------------------------------------
// Kernel 4a: pack f_s fp32 [b][c][s] -> fp16 [b][sb(32)][c][36]
// ---------------------------------------------------------------------------
__global__ __launch_bounds__(256) void k_fspack(const float* __restrict__ fsi,
                                                unsigned short* __restrict__ fsp) {
    int id = blockIdx.x * 256 + threadIdx.x;  // 0..65535
    int c = id & 511, sb = (id >> 9) & 31, b = id >> 14;
    const float4* src = (const float4*)(fsi + (((size_t)(b * 512 + c)) << 10) + sb * 32);
    unsigned short* dst = fsp + (size_t)((b * 32 + sb) * 512 + c) * 36;
#pragma unroll
    for (int j = 0; j < 8; ++j) {
        float4 v = src[j];
        uint2 r;
        r.x = (unsigned)f2h(v.x) | ((unsigned)f2h(v.y) << 16);
        r.y = (unsigned)f2h(v.z) | ((unsigned)f2h(v.w) << 16);
        *(uint2*)(dst + j * 4) = r;
    }
}

// ---------------------------------------------------------------------------
// Kernel 4b (MFMA f16): att_fq[b,c,q] = sum_s attn[q,s] * f_s[c,s]  (verified)
// ---------------------------------------------------------------------------
__global__ __launch_bounds__(256) void k_attfqm(const unsigned short* __restrict__ fsp,
                                                const unsigned short* __restrict__ attn,
                                                float* __restrict__ attfq) {
    __shared__ __align__(16) char L[2][14336];  // A 4608 B | B 9216 B | pad
    const int q0 = blockIdx.x * 128;
    const int c0 = blockIdx.y * 64;
    const int b  = blockIdx.z;
    const int t = threadIdx.x;
    const int w = t >> 6, lane = t & 63;
    const int quad = lane >> 4, m16 = lane & 15;

    f32x4_t acc[4][2];
#pragma unroll
    for (int i = 0; i < 4; ++i)
#pragma unroll
        for (int j = 0; j < 2; ++j) acc[i][j] = (f32x4_t){0.f, 0.f, 0.f, 0.f};

    auto stage = [&](int sb, int buf) {
        const char* sa = (const char*)(fsp + (size_t)((b * 32 + sb) * 512 + c0) * 36);
        const char* sbp = (const char*)(attn + (size_t)((b * 32 + sb) * 1024 + q0) * 36);
#pragma unroll
        for (int i = 0; i < 4; ++i) {
            int idx0 = i * 256 + w * 64;
            if (idx0 < 896) {
                int idx = idx0 + lane;
                const char* src = (idx < 288) ? (sa + idx * 16) : (sbp + (idx - 288) * 16);
                __builtin_amdgcn_global_load_lds(
                    (const __attribute__((address_space(1))) void*)src,
                    (__attribute__((address_space(3))) void*)(&L[buf][0] + idx0 * 16),
                    16, 0, 0);
            }
        }
    };

    stage(0, 0);
    for (int sb = 0; sb < 32; ++sb) {
        const int buf = sb & 1;
        __syncthreads();
        if (sb < 31) stage(sb + 1, buf ^ 1);
        const char* base = &L[buf][0];
        f16x8_t af[4], bfr[2];
#pragma unroll
        for (int i = 0; i < 4; ++i)
            af[i] = rd_frag36h(base + (size_t)(i * 16 + m16) * 72 + quad * 16);
#pragma unroll
        for (int ni = 0; ni < 2; ++ni)
            bfr[ni] = rd_frag36h(base + 4608 + (size_t)(w * 32 + ni * 16 + m16) * 72 + quad * 16);
#pragma unroll
        for (int mi = 0; mi < 4; ++mi)
#pragma unroll
            for (int ni = 0; ni < 2; ++ni)
                acc[mi][ni] = __builtin_amdgcn_mfma_f32_16x16x32_f16(
                    af[mi], bfr[ni], acc[mi][ni], 0, 0, 0);
    }

#pragma unroll
    for (int mi = 0; mi < 4; ++mi)
#pragma unroll
        for (int e = 0; e < 4; ++e) {
            int c = c0 + mi * 16 + quad * 4 + e;
            float* rowp = attfq + (((size_t)(b * 512 + c)) << 10) + q0 + w * 32 + m16;
#pragma unroll
            for (int ni = 0; ni < 2; ++ni)
                rowp[ni * 16] = acc[mi][ni][e];
        }
}

// ---------------------------------------------------------------------------
// Kernel 5: fq = l2n(f_q,C) + 0.5*l2n(att_fq,C). Grid (32,4): 32 pos x 8 cg.
// ---------------------------------------------------------------------------
__global__ __launch_bounds__(256) void k_out(const float* __restrict__ fqi,
                                             const float* __restrict__ attfq,
                                             float* __restrict__ out) {
    __shared__ float redq[256], reda[256];
    __shared__ float rnq[32], rna[32];
    const int b = blockIdx.y;
    const int p0 = blockIdx.x * 32;
    const int t = threadIdx.x;
    const int pl = t & 31, cg = t >> 5;
    const int pos = p0 + pl;
    const float* qp = fqi + (((size_t)b) << 19) + pos;
    const float* ap = attfq + (((size_t)b) << 19) + pos;
    float sq = 0.f, sa = 0.f;
    for (int c = cg * 64; c < cg * 64 + 64; ++c) {
        float q = qp[(size_t)c << 10];
        float a = ap[(size_t)c << 10];
        sq += q * q;
        sa += a * a;
    }
    redq[t] = sq; reda[t] = sa;
    __syncthreads();
    if (t < 32) {
        float q = 0.f, a = 0.f;
#pragma unroll
        for (int j = 0; j < 8; ++j) { q += redq[t + 32 * j]; a += reda[t + 32 * j]; }
        rnq[t] = 1.f / fmaxf(sqrtf(q), 1e-12f);
        rna[t] = 1.f / fmaxf(sqrtf(a), 1e-12f);
    }
    __syncthreads();
    const float RQ = rnq[pl], RA = 0.5f * rna[pl];
    float* o1 = out + (((size_t)b) << 19) + pos;
    float* o2 = o1 + 2097152;
    for (int c = cg * 64; c < cg * 64 + 64; ++c) {
        float q = qp[(size_t)c << 10];
        float a = ap[(size_t)c << 10];
        o1[(size_t)c << 10] = q * RQ + a * RA;
        o2[(size_t)c << 10] = a;
    }
}

// ---------------------------------------------------------------------------
// Kernel 6a: pack w1 fp32 [256 oc][1024 ic][9 tap] -> bf16 [tap][s][oc][36]
// ---------------------------------------------------------------------------
__global__ __launch_bounds__(256) void k_w1pack(const float* __restrict__ w1,
                                                unsigned short* __restrict__ w1p) {
    int pid = blockIdx.x * 256 + threadIdx.x;  // (oc,ic)
    int oc = pid >> 10, ic = pid & 1023;
    const float* src = w1 + (size_t)pid * 9;
    float f[9];
#pragma unroll
    for (int tp = 0; tp < 9; ++tp) f[tp] = src[tp];
    int s = ic >> 5, j = ic & 31;
#pragma unroll
    for (int tp = 0; tp < 9; ++tp) {
        size_t row = ((size_t)(tp * 32 + s) * 256 + oc) * 36;
        w1p[row + j] = f2bf(f[tp]);
        if (j < 4) w1p[row + 32 + j] = 0;
    }
}

// ---------------------------------------------------------------------------
// Kernel 6b (MFMA): conv1 partials, kh x ic-half split (z = khg*2+ich, 6 vals).
// 48 K-steps. B staged as bf16 [n][36]. Output fp16 P6[pp][b][oc][1024].
// ---------------------------------------------------------------------------
__global__ __launch_bounds__(256) void k_conv1m(const float* __restrict__ fqi,
                                                const float* __restrict__ fsi,
                                                const unsigned short* __restrict__ w1p,
                                                unsigned short* __restrict__ P6) {
    __shared__ __align__(16) char As[2][18432];            // [256 oc][36] bf16
    __shared__ __align__(16) unsigned short Bs[2][64 * 36];
    const int p0 = blockIdx.x * 64;
    const int b = blockIdx.y;
    const int khg = blockIdx.z >> 1;
    const int ich = blockIdx.z & 1;
    const int dy = 2 * khg - 2;
    const int t = threadIdx.x;
    const int w = t >> 6, lane = t & 63;
    const int quad = lane >> 4, m16 = lane & 15;
    const int sn = t & 63, soct = t >> 6;   // B staging: col, k-oct

    f32x4_t acc[4][4];
#pragma unroll
    for (int i = 0; i < 4; ++i)
#pragma unroll
        for (int j = 0; j < 4; ++j) acc[i][j] = (f32x4_t){0.f, 0.f, 0.f, 0.f};

    auto stageA = [&](int f, int buf) {
        int kw = f >> 4, s = ich * 16 + (f & 15);
        const char* src = (const char*)(w1p + (size_t)((khg * 3 + kw) * 32 + s) * 9216);
#pragma unroll
        for (int i = 0; i < 5; ++i) {
            int idx = i * 4 + w;
            if (idx < 18)
                __builtin_amdgcn_global_load_lds(
                    (const __attribute__((address_space(1))) void*)(src + idx * 1024 + lane * 16),
                    (__attribute__((address_space(3))) void*)(&As[buf][0] + idx * 1024),
                    16, 0, 0);
        }
    };
    auto stageB = [&](int f, int buf) {
        int kw = f >> 4, s = ich * 16 + (f & 15);
        int dx = 2 * kw - 2;
        int off = dy * 32 + dx;
        int ch0 = s * 32;
        const float* base = (ch0 < 512)
            ? (fqi + (((size_t)(b * 512 + ch0)) << 10))
            : (fsi + (((size_t)(b * 512 + ch0 - 512)) << 10));
        int e0 = p0 + sn;
        int y0 = e0 >> 5, x0 = e0 & 31;
        bool valid = ((unsigned)(y0 + dy) < 32u) && ((unsigned)(x0 + dx) < 32u);
        int c = min(max(e0 + off, 0), 1023);
        float f8[8];
#pragma unroll
        for (int j = 0; j < 8; ++j) {
            float v = base[(size_t)(soct * 8 + j) * 1024 + c];
            f8[j] = valid ? v : 0.f;
        }
        pack8_bf16(f8, &Bs[buf][0] + sn * 36 + soct * 8);
    };

    stageA(0, 0);
    stageB(0, 0);

    for (int f = 0; f < 48; ++f) {
        const int buf = f & 1;
        __syncthreads();
        if (f < 47) {
            stageA(f + 1, buf ^ 1);
            stageB(f + 1, buf ^ 1);
        }
        bf16x8_t af[4], bfr[4];
#pragma unroll
        for (int i = 0; i < 4; ++i) {
            af[i] = rd_frag36((const unsigned short*)&As[buf][0], w * 64 + i * 16 + m16, quad);
            bfr[i] = rd_frag36(&Bs[buf][0], i * 16 + m16, quad);
        }
#pragma unroll
        for (int mi = 0; mi < 4; ++mi)
#pragma unroll
            for (int ni = 0; ni < 4; ++ni)
                acc[mi][ni] = __builtin_amdgcn_mfma_f32_16x16x32_bf16(
                    af[mi], bfr[ni], acc[mi][ni], 0, 0, 0);
    }

    const int pp = khg * 2 + ich;
    unsigned short* Pb = P6 + (((size_t)(pp * 4 + b)) << 18) + p0;
#pragma unroll
    for (int mi = 0; mi < 4; ++mi)
#pragma unroll
        for (int e = 0; e < 4; ++e) {
            int oc = w * 64 + mi * 16 + quad * 4 + e;
            unsigned short* row = Pb + (size_t)oc * 1024 + m16;
#pragma unroll
            for (int ni = 0; ni < 4; ++ni)
                row[ni * 16] = f2h(acc[mi][ni][e]);
        }
}

// ---------------------------------------------------------------------------
// Kernel 6c: x1 = relu(sum of 6 fp16 partials + b1), stored bf16
// ---------------------------------------------------------------------------
__global__ __launch_bounds__(256) void k_c1comb(const unsigned short* __restrict__ P6,
                                                const float* __restrict__ b1,
                                                unsigned short* __restrict__ x1) {
    int id = blockIdx.x * 256 + threadIdx.x;  // 4-elem index, 0..262143
    int oc = (id >> 8) & 255;
    float s0 = 0.f, s1 = 0.f, s2 = 0.f, s3 = 0.f;
#pragma unroll
    for (int p = 0; p < 6; ++p) {
        uint2 v = *(const uint2*)(P6 + (size_t)p * 1048576 + (size_t)id * 4);
        s0 += h2f(v.x & 0xffff); s1 += h2f(v.x >> 16);
        s2 += h2f(v.y & 0xffff); s3 += h2f(v.y >> 16);
    }
    float bb = b1[oc];
    uint2 r;
    r.x = (unsigned)f2bf(fmaxf(s0 + bb, 0.f)) | ((unsigned)f2bf(fmaxf(s1 + bb, 0.f)) << 16);
    r.y = (unsigned)f2bf(fmaxf(s2 + bb, 0.f)) | ((unsigned)f2bf(fmaxf(s3 + bb, 0.f)) << 16);
    ((uint2*)x1)[id] = r;
}

// ---------------------------------------------------------------------------
// Kernel 7a: pack w2 fp32 [256 oc][256 ic][9 tap] -> bf16 [tap][s(8)][oc][36]
// ---------------------------------------------------------------------------
__global__ __launch_bounds__(256) void k_w2pack(const float* __restrict__ w2,
                                                unsigned short* __restrict__ w2p) {
    int pid = blockIdx.x * 256 + threadIdx.x;  // (oc,ic)
    int oc = pid >> 8, ic = pid & 255;
    const float* src = w2 + (size_t)pid * 9;
    float f[9];
#pragma unroll
    for (int tp = 0; tp < 9; ++tp) f[tp] = src[tp];
    int s = ic >> 5, j = ic & 31;
#pragma unroll
    for (int tp = 0; tp < 9; ++tp) {
        size_t row = ((size_t)(tp * 8 + s) * 256 + oc) * 36;
        w2p[row + j] = f2bf(f[tp]);
        if (j < 4) w2p[row + 32 + j] = 0;
    }
}

// ---------------------------------------------------------------------------
// Kernel 7b (MFMA): conv2 partials, kh x ic-half split (z = kh*2+ich).
// 12 K-steps. x1 bf16 copied straight into [n][36] LDS rows.
// ---------------------------------------------------------------------------
__global__ __launch_bounds__(256) void k_conv2m(const unsigned short* __restrict__ x1,
                                                const unsigned short* __restrict__ w2p,
                                                unsigned short* __restrict__ P6) {
    __shared__ __align__(16) char As[2][18432];
    __shared__ __align__(16) unsigned short Bs[2][64 * 36];
    const int p0 = blockIdx.x * 64;
    const int b = blockIdx.y;
    const int kh = blockIdx.z >> 1;
    const int ich = blockIdx.z & 1;
    const int t = threadIdx.x;
    const int w = t >> 6, lane = t & 63;
    const int quad = lane >> 4, m16 = lane & 15;
    const int sn = t & 63, soct = t >> 6;

    f32x4_t acc[4][4];
#pragma unroll
    for (int i = 0; i < 4; ++i)
#pragma unroll
        for (int j = 0; j < 4; ++j) acc[i][j] = (f32x4_t){0.f, 0.f, 0.f, 0.f};

    auto stageA = [&](int f, int buf) {
        int kw = f >> 2, s = ich * 4 + (f & 3);
        const char* src = (const char*)(w2p + (size_t)((kh * 3 + kw) * 8 + s) * 9216);
#pragma unroll
        for (int i = 0; i < 5; ++i) {
            int idx = i * 4 + w;
            if (idx < 18)
                __builtin_amdgcn_global_load_lds(
                    (const __attribute__((address_space(1))) void*)(src + idx * 1024 + lane * 16),
                    (__attribute__((address_space(3))) void*)(&As[buf][0] + idx * 1024),
                    16, 0, 0);
        }
    };
    auto stageB = [&](int f, int buf) {
        int kw = f >> 2, s = ich * 4 + (f & 3);
        int off = kh * 32 + kw;
        const unsigned short* base = x1 + (((size_t)(b * 256 + s * 32)) << 10);
        int c = min(p0 + sn + off, 1023);
        unsigned short v[8];
#pragma unroll
        for (int j = 0; j < 8; ++j)
            v[j] = base[(size_t)(soct * 8 + j) * 1024 + c];
        unsigned long long d0 = 0, d1 = 0;
#pragma unroll
        for (int j = 0; j < 4; ++j) {
            d0 |= (unsigned long long)v[j] << (16 * j);
            d1 |= (unsigned long long)v[4 + j] << (16 * j);
        }
        unsigned short* dp = &Bs[buf][0] + sn * 36 + soct * 8;
        *(unsigned long long*)dp = d0;
        *(unsigned long long*)(dp + 4) = d1;
    };

    stageA(0, 0);
    stageB(0, 0);

    for (int f = 0; f < 12; ++f) {
        const int buf = f & 1;
        __syncthreads();
        if (f < 11) {
            stageA(f + 1, buf ^ 1);
            stageB(f + 1, buf ^ 1);
        }
        bf16x8_t af[4], bfr[4];
#pragma unroll
        for (int i = 0; i < 4; ++i) {
            af[i] = rd_frag36((const unsigned short*)&As[buf][0], w * 64 + i * 16 + m16, quad);
            bfr[i] = rd_frag36(&Bs[buf][0], i * 16 + m16, quad);
        }
#pragma unroll
        for (int mi = 0; mi < 4; ++mi)
#pragma unroll
            for (int ni = 0; ni < 4; ++ni)
                acc[mi][ni] = __builtin_amdgcn_mfma_f32_16x16x32_bf16(
                    af[mi], bfr[ni], acc[mi][ni], 0, 0, 0);
    }

    const int pp = kh * 2 + ich;
    unsigned short* Pb = P6 + (((size_t)(pp * 4 + b)) << 18) + p0;
#pragma unroll
    for (int mi = 0; mi < 4; ++mi)
#pragma unroll
        for (int e = 0; e < 4; ++e) {
            int oc = w * 64 + mi * 16 + quad * 4 + e;
            unsigned short* row = Pb + (size_t)oc * 1024 + m16;
#pragma unroll
            for (int ni = 0; ni < 4; ++ni)
                row[ni * 16] = f2h(acc[mi][ni][e]);
        }
}

// ---------------------------------------------------------------------------
// Kernel 7c: combine 6 fp16 conv2 partials + bias, 3x3/3 maxpool -> xp
// ---------------------------------------------------------------------------
__global__ __launch_bounds__(256) void k_c2pool(const unsigned short* __restrict__ P6,
                                                const float* __restrict__ b2,
                                                float* __restrict__ xp) {
    int id = blockIdx.x * 256 + threadIdx.x;  // 0..102399
    int px = id % 10;
    int tmp = id / 10;
    int py = tmp % 10;
    int ch = tmp / 10;          // b*256 + oc
    int oc = ch & 255;
    float bb = b2[oc];
    const unsigned short* base = P6 + ((size_t)ch << 10);
    float m = -3.4e38f;
#pragma unroll
    for (int dy = 0; dy < 3; ++dy)
#pragma unroll
        for (int dx = 0; dx < 3; ++dx) {
            int pos = (3 * py + dy) * 32 + 3 * px + dx;
            float v = bb;
#pragma unroll
            for (int p = 0; p < 6; ++p)
                v += h2f(base[(size_t)p * 1048576 + pos]);
            m = fmaxf(m, v);
        }
    xp[id] = m;
}

// ---------------------------------------------------------------------------
// Kernel 9: conv3 (256ch, 10x10 -> 8x8) + spatial mean + b3 -> weight[1,B]
// ---------------------------------------------------------------------------
__global__ __launch_bounds__(256) void k_conv3(const float* __restrict__ xp,
                                               const float* __restrict__ w3,
                                               const float* __restrict__ b3,
                                               float* __restrict__ out) {
    __shared__ float s[256];
    int b = blockIdx.x, t = threadIdx.x;
    int pos = t & 63, qi = t >> 6;
    int y = pos >> 3, x = pos & 7;
    float acc = 0.f;
    for (int ic = qi * 64; ic < qi * 64 + 64; ++ic) {
        const float* ip = xp + ((size_t)(b * 256 + ic)) * 100 + y * 10 + x;
#pragma unroll
        for (int kh = 0; kh < 3; ++kh)
#pragma unroll
            for (int kw = 0; kw < 3; ++kw)
                acc = fmaf(w3[ic * 9 + kh * 3 + kw], ip[kh * 10 + kw], acc);
    }
    s[t] = acc;
    __syncthreads();
    if (t < 64) {
        float v = s[t] + s[t + 64] + s[t + 128] + s[t + 192];
#pragma unroll
        for (int off = 32; off >= 1; off >>= 1) v += __shfl_down(v, off);
        if (t == 0) out[4194304 + b] = v * (1.f / 64.f) + b3[0];
    }
}

// ---------------------------------------------------------------------------
extern "C" void kernel_launch(void* const* d_in, const int* in_sizes, int n_in,
                              void* d_out, int out_size, void* d_ws, size_t ws_size,
                              hipStream_t stream) {
    (void)in_sizes; (void)n_in; (void)out_size; (void)ws_size;
    const float* fqf = (const float*)d_in[0];
    const float* fsf = (const float*)d_in[1];
    const float* fqi = (const float*)d_in[2];
    const float* fsi = (const float*)d_in[3];
    const float* w1  = (const float*)d_in[4];
    const float* b1  = (const float*)d_in[5];
    const float* w2  = (const float*)d_in[6];
    const float* b2  = (const float*)d_in[7];
    const float* w3  = (const float*)d_in[8];
    const float* b3  = (const float*)d_in[9];
    float* out = (float*)d_out;

    float* W = (float*)d_ws;
    // [0 .. 4,194,304) f32: P01 fp16 (8.4M ush); aliased by conv1 P6 fp16
    //   (6.29M ush, pre-corr), attfq fp32 (2.1M, post-softmax), conv2 P6 fp16.
    unsigned short* P01u = (unsigned short*)W;
    unsigned short* P6u  = (unsigned short*)W;
    float* attfq = W;
    // [4,194,304 .. 6,553,600): attn fp16 padded; aliased by w1p (dead after
    //   conv1m), rq/rs (dead after k_corr), w2p (written after k_out).
    unsigned short* attn = (unsigned short*)(W + 4194304);
    unsigned short* w1p  = (unsigned short*)(W + 4194304);
    float* rq = W + 5521408;
    float* rs = W + 5558272;
    unsigned short* w2p  = (unsigned short*)(W + 4194304);
    // [6,553,600 .. 7,733,248): fsp fp16 padded
    unsigned short* fsp = (unsigned short*)(W + 6553600);
    // [7,733,248 .. 8,257,536): x1 bf16
    unsigned short* x1 = (unsigned short*)(W + 7733248);
    // [8,257,536 .. 8,359,936): xp fp32   (total 33.4 MB)
    float* xp = W + 8257536;

    hipLaunchKernelGGL(k_w1pack,  dim3(1024),      dim3(256), 0, stream, w1, w1p);
    hipLaunchKernelGGL(k_conv1m,  dim3(16, 4, 6),  dim3(256), 0, stream, fqi, fsi, w1p, P6u);
    hipLaunchKernelGGL(k_c1comb,  dim3(1024),      dim3(256), 0, stream, P6u, b1, x1);
    hipLaunchKernelGGL(k_fspack,  dim3(256),       dim3(256), 0, stream, fsi, fsp);
    hipLaunchKernelGGL(k_norms,   dim3(16, 72),    dim3(256), 0, stream, fqf, fsf, rq, rs);
    hipLaunchKernelGGL(k_corr,    dim3(8, 8, 8),   dim3(256), 0, stream, fqf, fsf, rq, rs, P01u);
    hipLaunchKernelGGL(k_softmax, dim3(4096),      dim3(256), 0, stream, P01u, attn);
    hipLaunchKernelGGL(k_attfqm,  dim3(8, 8, 4),   dim3(256), 0, stream, fsp, attn, attfq);
    hipLaunchKernelGGL(k_out,     dim3(32, 4),     dim3(256), 0, stream, fqi, attfq, out);
    hipLaunchKernelGGL(k_w2pack,  dim3(256),       dim3(256), 0, stream, w2, w2p);
    hipLaunchKernelGGL(k_conv2m,  dim3(16, 4, 6),  dim3(256), 0, stream, x1, w2p, P6u);
    hipLaunchKernelGGL(k_c2pool,  dim3(400),       dim3(256), 0, stream, P6u, b2, xp);
    hipLaunchKernelGGL(k_conv3,   dim3(4),         dim3(256), 0, stream, xp, w3, b3, out);
}